// Round 1
// baseline (1625.791 us; speedup 1.0000x reference)
//
#include <hip/hip_runtime.h>
#include <hip/hip_bf16.h>

#define SEQ   4096
#define NFFT  8192
#define NCH   768
#define NB    16
#define KST   4104            // Kf row stride in float2 units
#define LDSN  8704            // 8192 + 8192/16 padding

__device__ __forceinline__ int phys(int p) { return p + (p >> 4); }
__device__ __forceinline__ int br13(int k) { return (int)(__brev((unsigned)k) >> 19); }

__device__ __constant__ int BR4[16] = {0,8,4,12,2,10,6,14,1,9,5,13,3,11,7,15};

__device__ __forceinline__ float2 cmulf(float2 a, float2 b) {
  return make_float2(a.x*b.x - a.y*b.y, a.x*b.y + a.y*b.x);
}

// forward DIF butterfly: a' = a+b ; b' = (a-b)*w
__device__ __forceinline__ void bf_f(float2& a, float2& b, float wx, float wy) {
  float tx = a.x - b.x, ty = a.y - b.y;
  a.x += b.x; a.y += b.y;
  b.x = tx*wx - ty*wy;
  b.y = tx*wy + ty*wx;
}
// inverse (doubling) DIT butterfly with conj(w) applied internally:
// given L=a, U=b (outputs of bf_f), recovers (2a, 2b)
__device__ __forceinline__ void bf_i(float2& a, float2& b, float wx, float wy) {
  float bx = b.x*wx + b.y*wy;
  float by = b.y*wx - b.x*wy;
  b.x = a.x - bx; b.y = a.y - by;
  a.x += bx; a.y += by;
}

#define C1X 0.9238795325112867f
#define C1Y (-0.3826834323650898f)
#define C2X 0.7071067811865476f
#define C2Y (-0.7071067811865476f)
#define C3X 0.3826834323650898f
#define C3Y (-0.9238795325112867f)

// 16-point DIF DFT: natural-in, bitrev4-slot-out
__device__ __forceinline__ void dft16_f(float2 v[16]) {
  // span 8, w16^s
  bf_f(v[0], v[8],  1.f, 0.f);
  bf_f(v[1], v[9],  C1X, C1Y);
  bf_f(v[2], v[10], C2X, C2Y);
  bf_f(v[3], v[11], C3X, C3Y);
  bf_f(v[4], v[12], 0.f, -1.f);
  bf_f(v[5], v[13], -C3X, C3Y);
  bf_f(v[6], v[14], -C2X, C2Y);
  bf_f(v[7], v[15], -C1X, C1Y);
  // span 4, w8^s
  bf_f(v[0], v[4],  1.f, 0.f);  bf_f(v[1], v[5],  C2X, C2Y);
  bf_f(v[2], v[6],  0.f, -1.f); bf_f(v[3], v[7],  -C2X, C2Y);
  bf_f(v[8], v[12], 1.f, 0.f);  bf_f(v[9], v[13], C2X, C2Y);
  bf_f(v[10],v[14], 0.f, -1.f); bf_f(v[11],v[15], -C2X, C2Y);
  // span 2, w4^s
  bf_f(v[0], v[2], 1.f, 0.f);  bf_f(v[1], v[3], 0.f, -1.f);
  bf_f(v[4], v[6], 1.f, 0.f);  bf_f(v[5], v[7], 0.f, -1.f);
  bf_f(v[8], v[10],1.f, 0.f);  bf_f(v[9], v[11],0.f, -1.f);
  bf_f(v[12],v[14],1.f, 0.f);  bf_f(v[13],v[15],0.f, -1.f);
  // span 1
  bf_f(v[0], v[1], 1.f, 0.f);  bf_f(v[2], v[3], 1.f, 0.f);
  bf_f(v[4], v[5], 1.f, 0.f);  bf_f(v[6], v[7], 1.f, 0.f);
  bf_f(v[8], v[9], 1.f, 0.f);  bf_f(v[10],v[11],1.f, 0.f);
  bf_f(v[12],v[13],1.f, 0.f);  bf_f(v[14],v[15],1.f, 0.f);
}

// unnormalized inverse: bitrev4-slot-in, natural-out, scaled x16
__device__ __forceinline__ void dft16_i(float2 v[16]) {
  // span 1
  bf_i(v[0], v[1], 1.f, 0.f);  bf_i(v[2], v[3], 1.f, 0.f);
  bf_i(v[4], v[5], 1.f, 0.f);  bf_i(v[6], v[7], 1.f, 0.f);
  bf_i(v[8], v[9], 1.f, 0.f);  bf_i(v[10],v[11],1.f, 0.f);
  bf_i(v[12],v[13],1.f, 0.f);  bf_i(v[14],v[15],1.f, 0.f);
  // span 2
  bf_i(v[0], v[2], 1.f, 0.f);  bf_i(v[1], v[3], 0.f, -1.f);
  bf_i(v[4], v[6], 1.f, 0.f);  bf_i(v[5], v[7], 0.f, -1.f);
  bf_i(v[8], v[10],1.f, 0.f);  bf_i(v[9], v[11],0.f, -1.f);
  bf_i(v[12],v[14],1.f, 0.f);  bf_i(v[13],v[15],0.f, -1.f);
  // span 4
  bf_i(v[0], v[4],  1.f, 0.f);  bf_i(v[1], v[5],  C2X, C2Y);
  bf_i(v[2], v[6],  0.f, -1.f); bf_i(v[3], v[7],  -C2X, C2Y);
  bf_i(v[8], v[12], 1.f, 0.f);  bf_i(v[9], v[13], C2X, C2Y);
  bf_i(v[10],v[14], 0.f, -1.f); bf_i(v[11],v[15], -C2X, C2Y);
  // span 8
  bf_i(v[0], v[8],  1.f, 0.f);
  bf_i(v[1], v[9],  C1X, C1Y);
  bf_i(v[2], v[10], C2X, C2Y);
  bf_i(v[3], v[11], C3X, C3Y);
  bf_i(v[4], v[12], 0.f, -1.f);
  bf_i(v[5], v[13], -C3X, C3Y);
  bf_i(v[6], v[14], -C2X, C2Y);
  bf_i(v[7], v[15], -C1X, C1Y);
}

template<int NP>
__device__ __forceinline__ void pass_f(float2* X, int tid) {
  constexpr int G = NP / 16;
  #pragma unroll
  for (int gg = 0; gg < 2; ++gg) {
    int g = tid + gg * 256;
    int i = g % G;
    int base = (g / G) * NP + i;
    float2 v[16];
    #pragma unroll
    for (int m = 0; m < 16; ++m) v[m] = X[phys(base + m * G)];
    dft16_f(v);
    if (i) {
      float sn, cs; sincosf(-6.283185307179586f * (float)i / (float)NP, &sn, &cs);
      float2 w1 = make_float2(cs, sn), wr = w1;
      #pragma unroll
      for (int r = 1; r < 16; ++r) { v[BR4[r]] = cmulf(v[BR4[r]], wr); wr = cmulf(wr, w1); }
    }
    #pragma unroll
    for (int s = 0; s < 16; ++s) X[phys(base + s * G)] = v[s];
  }
}

template<int NP>
__device__ __forceinline__ void pass_i(float2* X, int tid) {
  constexpr int G = NP / 16;
  #pragma unroll
  for (int gg = 0; gg < 2; ++gg) {
    int g = tid + gg * 256;
    int i = g % G;
    int base = (g / G) * NP + i;
    float2 v[16];
    #pragma unroll
    for (int s = 0; s < 16; ++s) v[s] = X[phys(base + s * G)];
    if (i) {
      float sn, cs; sincosf(6.283185307179586f * (float)i / (float)NP, &sn, &cs);
      float2 w1 = make_float2(cs, sn), wr = w1;
      #pragma unroll
      for (int r = 1; r < 16; ++r) { v[BR4[r]] = cmulf(v[BR4[r]], wr); wr = cmulf(wr, w1); }
    }
    dft16_i(v);
    #pragma unroll
    for (int m = 0; m < 16; ++m) X[phys(base + m * G)] = v[m];
  }
}

__device__ __forceinline__ void pass_r2(float2* X, int tid) {
  for (int t = tid; t < 4096; t += 256) {
    int p0 = phys(2 * t), p1 = phys(2 * t + 1);
    float2 a = X[p0], b = X[p1];
    X[p0] = make_float2(a.x + b.x, a.y + b.y);
    X[p1] = make_float2(a.x - b.x, a.y - b.y);
  }
}

__device__ __forceinline__ void fft_forward(float2* X, int tid) {
  pass_f<8192>(X, tid); __syncthreads();
  pass_f<512>(X, tid);  __syncthreads();
  pass_f<32>(X, tid);   __syncthreads();
  pass_r2(X, tid);      __syncthreads();
}
__device__ __forceinline__ void fft_inverse(float2* X, int tid) {
  pass_r2(X, tid);      __syncthreads();
  pass_i<32>(X, tid);   __syncthreads();
  pass_i<512>(X, tid);  __syncthreads();
  pass_i<8192>(X, tid); __syncthreads();
}

// ---------------- kernel 1: implicit filter + FFT -> half spectra -----------
__global__ __launch_bounds__(256) void filter_fft_kernel(
    const float* __restrict__ w1, const float* __restrict__ b1,
    const float* __restrict__ w2, const float* __restrict__ b2,
    const float* __restrict__ w3, const float* __restrict__ b3,
    const float* __restrict__ freq, const float* __restrict__ deltas,
    float2* __restrict__ Kf) {
  __shared__ float2 X[LDSN];
  __shared__ float sw1[48], sb1[16], sw2[256], sb2[16], sfq[16], sw3[32];
  int tid = threadIdx.x;
  int c0 = 2 * blockIdx.x;
  if (tid < 48) sw1[tid] = w1[tid];
  if (tid < 16) { sb1[tid] = b1[tid]; sb2[tid] = b2[tid]; sfq[tid] = freq[tid]; }
  if (tid < 256) sw2[tid] = w2[tid];
  if (tid < 32) sw3[tid] = w3[(size_t)c0 * 16 + tid];
  float B30 = b3[c0], B31 = b3[c0 + 1];
  float D0 = deltas[c0], D1 = deltas[c0 + 1];
  __syncthreads();

  for (int idx = tid; idx < SEQ; idx += 256) {
    float t  = (float)idx * (1.0f / 4095.0f);
    float w  = 6.283185307179586f * (float)idx / 4096.0f;
    float fw = 1e-4f * w;
    float z0 = t, z1 = cosf(fw), z2 = -sinf(fw);
    float h1[16], h2[16];
    #pragma unroll
    for (int r = 0; r < 16; ++r)
      h1[r] = sinf(sfq[r] * (z0 * sw1[3*r] + z1 * sw1[3*r+1] + z2 * sw1[3*r+2] + sb1[r]));
    #pragma unroll
    for (int r = 0; r < 16; ++r) {
      float acc = sb2[r];
      #pragma unroll
      for (int s = 0; s < 16; ++s) acc += h1[s] * sw2[16*r + s];
      h2[r] = sinf(sfq[r] * acc);
    }
    float k0 = B30, k1 = B31;
    #pragma unroll
    for (int r = 0; r < 16; ++r) { k0 += h2[r] * sw3[r]; k1 += h2[r] * sw3[16 + r]; }
    k0 *= expf(-t * D0);
    k1 *= expf(-t * D1);
    X[phys(idx)] = make_float2(k0, k1);
  }
  for (int idx = SEQ + tid; idx < NFFT; idx += 256) X[phys(idx)] = make_float2(0.f, 0.f);
  __syncthreads();

  fft_forward(X, tid);

  // Hermitian unpack of packed pair + scale 1/(2*N^2); store bins 0..4096
  const float SC = 0.5f / 67108864.0f;
  for (int k = tid; k < 4097; k += 256) {
    int p = phys(br13(k));
    int q = phys(br13((NFFT - k) & (NFFT - 1)));
    float2 Xp = X[p], Xq = X[q];
    float2 K0 = make_float2(SC * (Xp.x + Xq.x), SC * (Xp.y - Xq.y));
    float2 K1 = make_float2(SC * (Xp.y + Xq.y), SC * (Xq.x - Xp.x));
    Kf[(size_t)c0 * KST + k]       = K0;
    Kf[(size_t)(c0 + 1) * KST + k] = K1;
  }
}

// ---------------- kernel 2: u[B,L,CH] -> bf16 ut[B,CH,L] --------------------
__global__ __launch_bounds__(256) void transpose_in(
    const float* __restrict__ u, __hip_bfloat16* __restrict__ ut) {
  __shared__ float tile[64][65];
  int i0 = blockIdx.x * 64, c0 = blockIdx.y * 64, b = blockIdx.z;
  int tr = threadIdx.x >> 6, tc = threadIdx.x & 63;
  const float* up = u + ((size_t)b * SEQ + i0) * NCH + c0;
  for (int r = tr; r < 64; r += 4) tile[r][tc] = up[(size_t)r * NCH + tc];
  __syncthreads();
  __hip_bfloat16* op = ut + ((size_t)b * NCH + c0) * SEQ + i0;
  for (int r = tr; r < 64; r += 4) op[(size_t)r * SEQ + tc] = __float2bfloat16(tile[tc][r]);
}

// ---------------- kernel 3: FFT conv per (batch, channel-pair), in place ----
__global__ __launch_bounds__(256) void conv_kernel(
    __hip_bfloat16* __restrict__ ut, const float2* __restrict__ Kf) {
  __shared__ float2 X[LDSN];
  int tid = threadIdx.x;
  int c0 = 2 * blockIdx.x;
  int b  = blockIdx.y;
  __hip_bfloat16* row = ut + ((size_t)b * NCH + c0) * SEQ;

  for (int idx = tid; idx < SEQ; idx += 256)
    X[phys(idx)] = make_float2(__bfloat162float(row[idx]),
                               __bfloat162float(row[SEQ + idx]));
  for (int idx = SEQ + tid; idx < NFFT; idx += 256) X[phys(idx)] = make_float2(0.f, 0.f);
  __syncthreads();

  fft_forward(X, tid);

  const float2* K0p = Kf + (size_t)c0 * KST;
  const float2* K1p = Kf + (size_t)(c0 + 1) * KST;
  for (int k = tid; k < 4097; k += 256) {
    int p = phys(br13(k));
    int q = phys(br13((NFFT - k) & (NFFT - 1)));
    float2 Xp = X[p], Xq = X[q];
    float2 U0 = make_float2(0.5f * (Xp.x + Xq.x), 0.5f * (Xp.y - Xq.y));
    float2 U1 = make_float2(0.5f * (Xp.y + Xq.y), 0.5f * (Xq.x - Xp.x));
    float2 K0 = K0p[k], K1 = K1p[k];
    float2 P0 = cmulf(U0, K0), P1 = cmulf(U1, K1);
    X[p] = make_float2(P0.x - P1.y, P0.y + P1.x);
    X[q] = make_float2(P0.x + P1.y, P1.x - P0.y);
  }
  __syncthreads();

  fft_inverse(X, tid);

  for (int n = tid; n < SEQ; n += 256) {
    float2 z = X[phys(n)];
    row[n]       = __float2bfloat16(z.x);
    row[SEQ + n] = __float2bfloat16(z.y);
  }
}

// ---------------- kernel 4: yt[B,CH,L] -> y[B,L,CH], fused + u*bias ---------
__global__ __launch_bounds__(256) void transpose_out(
    const __hip_bfloat16* __restrict__ yt, const float* __restrict__ u,
    const float* __restrict__ bias, float* __restrict__ y) {
  __shared__ float tile[64][65];
  int i0 = blockIdx.x * 64, c0 = blockIdx.y * 64, b = blockIdx.z;
  int tr = threadIdx.x >> 6, tc = threadIdx.x & 63;
  const __hip_bfloat16* yp = yt + ((size_t)b * NCH + c0) * SEQ + i0;
  for (int r = tr; r < 64; r += 4) tile[r][tc] = __bfloat162float(yp[(size_t)r * SEQ + tc]);
  __syncthreads();
  float bi = bias[c0 + tc];
  const float* up = u + ((size_t)b * SEQ + i0) * NCH + c0;
  float* op = y + ((size_t)b * SEQ + i0) * NCH + c0;
  for (int r = tr; r < 64; r += 4)
    op[(size_t)r * NCH + tc] = tile[tc][r] + up[(size_t)r * NCH + tc] * bi;
}

extern "C" void kernel_launch(void* const* d_in, const int* in_sizes, int n_in,
                              void* d_out, int out_size, void* d_ws, size_t ws_size,
                              hipStream_t stream) {
  const float* u      = (const float*)d_in[0];
  const float* w1     = (const float*)d_in[1];
  const float* b1     = (const float*)d_in[2];
  const float* w2     = (const float*)d_in[3];
  const float* b2     = (const float*)d_in[4];
  const float* w3     = (const float*)d_in[5];
  const float* b3     = (const float*)d_in[6];
  const float* freq   = (const float*)d_in[7];
  const float* deltas = (const float*)d_in[8];
  const float* bias   = (const float*)d_in[9];
  float* out = (float*)d_out;

  __hip_bfloat16* ut = (__hip_bfloat16*)d_ws;                         // 100,663,296 B
  float2* Kf = (float2*)((char*)d_ws + (size_t)NB * NCH * SEQ * 2);   // 25,214,976 B

  filter_fft_kernel<<<dim3(NCH / 2), dim3(256), 0, stream>>>(w1, b1, w2, b2, w3, b3, freq, deltas, Kf);
  transpose_in<<<dim3(SEQ / 64, NCH / 64, NB), dim3(256), 0, stream>>>(u, ut);
  conv_kernel<<<dim3(NCH / 2, NB), dim3(256), 0, stream>>>(ut, Kf);
  transpose_out<<<dim3(SEQ / 64, NCH / 64, NB), dim3(256), 0, stream>>>(ut, u, bias, out);
}

// Round 2
// 1149.987 us; speedup vs baseline: 1.4137x; 1.4137x over previous
//
#include <hip/hip_runtime.h>
#include <hip/hip_bf16.h>

#define SEQ   4096
#define NFFT  8192
#define NCH   768
#define NB    16
#define KST   4104            // Kf row stride in float2 units (bins 0..4096 + pad)
#define LDSN  4368            // phys(4095)=4365

// padding spreads both stride-16 (->17) and stride-256 (->273) lane patterns
__device__ __forceinline__ int phys(int p) { return p + (p >> 4) + (p >> 8); }
__device__ __forceinline__ int br12(int k) { return (int)(__brev((unsigned)k) >> 20); }

__device__ __constant__ int BR4[16] = {0,8,4,12,2,10,6,14,1,9,5,13,3,11,7,15};

__device__ __forceinline__ float2 cmulf(float2 a, float2 b) {
  return make_float2(a.x*b.x - a.y*b.y, a.x*b.y + a.y*b.x);
}

// forward DIF butterfly: a' = a+b ; b' = (a-b)*w
__device__ __forceinline__ void bf_f(float2& a, float2& b, float wx, float wy) {
  float tx = a.x - b.x, ty = a.y - b.y;
  a.x += b.x; a.y += b.y;
  b.x = tx*wx - ty*wy;
  b.y = tx*wy + ty*wx;
}
// inverse DIT butterfly (conj twiddle internal, unnormalized)
__device__ __forceinline__ void bf_i(float2& a, float2& b, float wx, float wy) {
  float bx = b.x*wx + b.y*wy;
  float by = b.y*wx - b.x*wy;
  b.x = a.x - bx; b.y = a.y - by;
  a.x += bx; a.y += by;
}

#define C1X 0.9238795325112867f
#define C1Y (-0.3826834323650898f)
#define C2X 0.7071067811865476f
#define C2Y (-0.7071067811865476f)
#define C3X 0.3826834323650898f
#define C3Y (-0.9238795325112867f)

// spans 4,2,1 of the 16-pt DIF DFT (natural-in, bitrev4-slot-out overall)
__device__ __forceinline__ void dft16_f_tail(float2 v[16]) {
  // span 4, w8^s
  bf_f(v[0], v[4],  1.f, 0.f);  bf_f(v[1], v[5],  C2X, C2Y);
  bf_f(v[2], v[6],  0.f, -1.f); bf_f(v[3], v[7],  -C2X, C2Y);
  bf_f(v[8], v[12], 1.f, 0.f);  bf_f(v[9], v[13], C2X, C2Y);
  bf_f(v[10],v[14], 0.f, -1.f); bf_f(v[11],v[15], -C2X, C2Y);
  // span 2, w4^s
  bf_f(v[0], v[2], 1.f, 0.f);  bf_f(v[1], v[3], 0.f, -1.f);
  bf_f(v[4], v[6], 1.f, 0.f);  bf_f(v[5], v[7], 0.f, -1.f);
  bf_f(v[8], v[10],1.f, 0.f);  bf_f(v[9], v[11],0.f, -1.f);
  bf_f(v[12],v[14],1.f, 0.f);  bf_f(v[13],v[15],0.f, -1.f);
  // span 1
  bf_f(v[0], v[1], 1.f, 0.f);  bf_f(v[2], v[3], 1.f, 0.f);
  bf_f(v[4], v[5], 1.f, 0.f);  bf_f(v[6], v[7], 1.f, 0.f);
  bf_f(v[8], v[9], 1.f, 0.f);  bf_f(v[10],v[11],1.f, 0.f);
  bf_f(v[12],v[13],1.f, 0.f);  bf_f(v[14],v[15],1.f, 0.f);
}

__device__ __forceinline__ void dft16_f(float2 v[16]) {
  bf_f(v[0], v[8],  1.f, 0.f);
  bf_f(v[1], v[9],  C1X, C1Y);
  bf_f(v[2], v[10], C2X, C2Y);
  bf_f(v[3], v[11], C3X, C3Y);
  bf_f(v[4], v[12], 0.f, -1.f);
  bf_f(v[5], v[13], -C3X, C3Y);
  bf_f(v[6], v[14], -C2X, C2Y);
  bf_f(v[7], v[15], -C1X, C1Y);
  dft16_f_tail(v);
}

// inverse: bitrev4-slot-in, natural-out, scaled x16
__device__ __forceinline__ void dft16_i(float2 v[16]) {
  // span 1
  bf_i(v[0], v[1], 1.f, 0.f);  bf_i(v[2], v[3], 1.f, 0.f);
  bf_i(v[4], v[5], 1.f, 0.f);  bf_i(v[6], v[7], 1.f, 0.f);
  bf_i(v[8], v[9], 1.f, 0.f);  bf_i(v[10],v[11],1.f, 0.f);
  bf_i(v[12],v[13],1.f, 0.f);  bf_i(v[14],v[15],1.f, 0.f);
  // span 2
  bf_i(v[0], v[2], 1.f, 0.f);  bf_i(v[1], v[3], 0.f, -1.f);
  bf_i(v[4], v[6], 1.f, 0.f);  bf_i(v[5], v[7], 0.f, -1.f);
  bf_i(v[8], v[10],1.f, 0.f);  bf_i(v[9], v[11],0.f, -1.f);
  bf_i(v[12],v[14],1.f, 0.f);  bf_i(v[13],v[15],0.f, -1.f);
  // span 4
  bf_i(v[0], v[4],  1.f, 0.f);  bf_i(v[1], v[5],  C2X, C2Y);
  bf_i(v[2], v[6],  0.f, -1.f); bf_i(v[3], v[7],  -C2X, C2Y);
  bf_i(v[8], v[12], 1.f, 0.f);  bf_i(v[9], v[13], C2X, C2Y);
  bf_i(v[10],v[14], 0.f, -1.f); bf_i(v[11],v[15], -C2X, C2Y);
  // span 8
  bf_i(v[0], v[8],  1.f, 0.f);
  bf_i(v[1], v[9],  C1X, C1Y);
  bf_i(v[2], v[10], C2X, C2Y);
  bf_i(v[3], v[11], C3X, C3Y);
  bf_i(v[4], v[12], 0.f, -1.f);
  bf_i(v[5], v[13], -C3X, C3Y);
  bf_i(v[6], v[14], -C2X, C2Y);
  bf_i(v[7], v[15], -C1X, C1Y);
}

__device__ __forceinline__ void twiddle_f(float2 v[16], int i, float invNP) {
  float sn, cs; __sincosf(-6.283185307179586f * (float)i * invNP, &sn, &cs);
  float2 w1 = make_float2(cs, sn), wr = w1;
  #pragma unroll
  for (int r = 1; r < 16; ++r) { v[BR4[r]] = cmulf(v[BR4[r]], wr); wr = cmulf(wr, w1); }
}
__device__ __forceinline__ void twiddle_i(float2 v[16], int i, float invNP) {
  float sn, cs; __sincosf(6.283185307179586f * (float)i * invNP, &sn, &cs);
  float2 w1 = make_float2(cs, sn), wr = w1;
  #pragma unroll
  for (int r = 1; r < 16; ++r) { v[BR4[r]] = cmulf(v[BR4[r]], wr); wr = cmulf(wr, w1); }
}

// first forward pass (NP=4096,G=256), input known zero for indices >= 2048
__device__ __forceinline__ void pass_f_first(float2* X, int tid) {
  float2 v[16];
  #pragma unroll
  for (int m = 0; m < 8; ++m) v[m] = X[phys(tid + m * 256)];
  v[8]  = v[0];
  v[9]  = cmulf(v[1], make_float2(C1X, C1Y));
  v[10] = cmulf(v[2], make_float2(C2X, C2Y));
  v[11] = cmulf(v[3], make_float2(C3X, C3Y));
  v[12] = make_float2(v[4].y, -v[4].x);
  v[13] = cmulf(v[5], make_float2(-C3X, C3Y));
  v[14] = cmulf(v[6], make_float2(-C2X, C2Y));
  v[15] = cmulf(v[7], make_float2(-C1X, C1Y));
  dft16_f_tail(v);
  if (tid) twiddle_f(v, tid, 1.0f / 4096.0f);
  #pragma unroll
  for (int s = 0; s < 16; ++s) X[phys(tid + s * 256)] = v[s];
}

template<int NP>
__device__ __forceinline__ void pass_f(float2* X, int tid) {
  constexpr int G = NP / 16;
  int i = tid & (G - 1);
  int base = (tid & ~(G - 1)) * 16 + i;
  float2 v[16];
  #pragma unroll
  for (int m = 0; m < 16; ++m) v[m] = X[phys(base + m * G)];
  dft16_f(v);
  if (G > 1 && i) twiddle_f(v, i, 1.0f / (float)NP);
  #pragma unroll
  for (int s = 0; s < 16; ++s) X[phys(base + s * G)] = v[s];
}

template<int NP>
__device__ __forceinline__ void pass_i(float2* X, int tid) {
  constexpr int G = NP / 16;
  int i = tid & (G - 1);
  int base = (tid & ~(G - 1)) * 16 + i;
  float2 v[16];
  #pragma unroll
  for (int s = 0; s < 16; ++s) v[s] = X[phys(base + s * G)];
  if (G > 1 && i) twiddle_i(v, i, 1.0f / (float)NP);
  dft16_i(v);
  #pragma unroll
  for (int m = 0; m < 16; ++m) X[phys(base + m * G)] = v[m];
}

__device__ __forceinline__ void fft_forward(float2* X, int tid) {
  pass_f_first(X, tid); __syncthreads();
  pass_f<256>(X, tid);  __syncthreads();
  pass_f<16>(X, tid);   __syncthreads();
}
__device__ __forceinline__ void fft_inverse(float2* X, int tid) {
  pass_i<16>(X, tid);   __syncthreads();
  pass_i<256>(X, tid);  __syncthreads();
  pass_i<4096>(X, tid); __syncthreads();
}

// rfft-halving unpack: given packed spectrum pair (Zk at spec k, Zq at spec (N-k)%N),
// produce X[k], X[N-k] of the length-8192 real FFT. c_=cos(pi k/4096), s_=sin.
__device__ __forceinline__ void unpack_pair(float2 Zk, float2 Zq, float c_, float s_,
                                            float2& Xk, float2& Xm) {
  float Ex = 0.5f*(Zk.x + Zq.x), Ey = 0.5f*(Zk.y - Zq.y);
  float Ox = 0.5f*(Zk.y + Zq.y), Oy = 0.5f*(Zq.x - Zk.x);
  Xk = make_float2(Ex + c_*Ox + s_*Oy,  Ey + c_*Oy - s_*Ox);
  Xm = make_float2(Ex - c_*Ox - s_*Oy, -Ey + c_*Oy - s_*Ox);
}

__device__ __forceinline__ float2 bf16pair_to_f2(unsigned int v) {
  return make_float2(__uint_as_float(v << 16), __uint_as_float(v & 0xFFFF0000u));
}
__device__ __forceinline__ unsigned int f2_to_bf16pair(float2 z) {
  unsigned int a = __float_as_uint(z.x), b = __float_as_uint(z.y);
  a = (a + 0x7FFFu + ((a >> 16) & 1u)) >> 16;
  b = (b + 0x7FFFu + ((b >> 16) & 1u)) & 0xFFFF0000u;
  return a | b;
}

// ---------------- kernel 1: implicit filter + FFT -> half spectrum ----------
__device__ __forceinline__ float mlp_eval(int n, const float* sw1, const float* sb1,
    const float* sw2, const float* sb2, const float* sfq, const float* sw3,
    float B3, float D) {
  float t = (float)n * (1.0f / 4095.0f);
  float fw = 1e-4f * 6.283185307179586f * (float)n / 4096.0f;
  float sfw, cfw; __sincosf(fw, &sfw, &cfw);
  float z0 = t, z1 = cfw, z2 = -sfw;
  float h1[16], h2[16];
  #pragma unroll
  for (int r = 0; r < 16; ++r)
    h1[r] = __sinf(sfq[r] * (z0 * sw1[3*r] + z1 * sw1[3*r+1] + z2 * sw1[3*r+2] + sb1[r]));
  #pragma unroll
  for (int r = 0; r < 16; ++r) {
    float acc = sb2[r];
    #pragma unroll
    for (int s = 0; s < 16; ++s) acc += h1[s] * sw2[16*r + s];
    h2[r] = __sinf(sfq[r] * acc);
  }
  float k = B3;
  #pragma unroll
  for (int r = 0; r < 16; ++r) k += h2[r] * sw3[r];
  return k * __expf(-t * D);
}

__global__ __launch_bounds__(256) void filter_fft_kernel(
    const float* __restrict__ w1, const float* __restrict__ b1,
    const float* __restrict__ w2, const float* __restrict__ b2,
    const float* __restrict__ w3, const float* __restrict__ b3,
    const float* __restrict__ freq, const float* __restrict__ deltas,
    float2* __restrict__ Kf) {
  __shared__ float2 X[LDSN];
  __shared__ float sw1[48], sb1[16], sw2[256], sb2[16], sfq[16], sw3[16];
  int tid = threadIdx.x;
  int c = blockIdx.x;
  if (tid < 48) sw1[tid] = w1[tid];
  if (tid < 16) { sb1[tid] = b1[tid]; sb2[tid] = b2[tid]; sfq[tid] = freq[tid];
                  sw3[tid] = w3[(size_t)c * 16 + tid]; }
  sw2[tid] = w2[tid];
  float B3 = b3[c], D = deltas[c];
  __syncthreads();

  // pack even/odd filter samples as complex; upper half (n2>=2048) stays unwritten (zero)
  #pragma unroll
  for (int j = 0; j < 8; ++j) {
    int n2 = tid + 256 * j;
    float k0 = mlp_eval(2*n2,     sw1, sb1, sw2, sb2, sfq, sw3, B3, D);
    float k1 = mlp_eval(2*n2 + 1, sw1, sb1, sw2, sb2, sfq, sw3, B3, D);
    X[phys(n2)] = make_float2(k0, k1);
  }
  __syncthreads();

  fft_forward(X, tid);

  const float SC = 1.0f / 33554432.0f;   // 1/(8192*4096)
  float2* Kc = Kf + (size_t)c * KST;
  for (int k = tid; k <= 2048; k += 256) {
    int kq = (4096 - k) & 4095;
    float2 Zk = X[phys(br12(k))], Zq = X[phys(br12(kq))];
    float c_, s_; __sincosf((float)k * (3.14159265358979e0f / 4096.0f), &s_, &c_);
    float2 Xk, Xm;
    unpack_pair(Zk, Zq, c_, s_, Xk, Xm);
    Kc[k]        = make_float2(SC * Xk.x, SC * Xk.y);
    Kc[4096 - k] = make_float2(SC * Xm.x, SC * Xm.y);
  }
}

// ---------------- kernel 2: u[B,L,CH] -> bf16 ut[B,CH,L] --------------------
__global__ __launch_bounds__(256) void transpose_in(
    const float* __restrict__ u, __hip_bfloat16* __restrict__ ut) {
  __shared__ float tile[64][65];
  int i0 = blockIdx.x * 64, c0 = blockIdx.y * 64, b = blockIdx.z;
  int tr = threadIdx.x >> 6, tc = threadIdx.x & 63;
  const float* up = u + ((size_t)b * SEQ + i0) * NCH + c0;
  for (int r = tr; r < 64; r += 4) tile[r][tc] = up[(size_t)r * NCH + tc];
  __syncthreads();
  __hip_bfloat16* op = ut + ((size_t)b * NCH + c0) * SEQ + i0;
  for (int r = tr; r < 64; r += 4) op[(size_t)r * SEQ + tc] = __float2bfloat16(tile[tc][r]);
}

// ---------------- kernel 3: FFT conv per (batch, channel), in place ---------
__global__ __launch_bounds__(256, 4) void conv_kernel(
    __hip_bfloat16* __restrict__ ut, const float2* __restrict__ Kf) {
  __shared__ float2 X[LDSN];
  int tid = threadIdx.x;
  int c = blockIdx.x;
  int b = blockIdx.y;
  unsigned int* row = (unsigned int*)(ut + ((size_t)b * NCH + c) * SEQ);

  // load 4096 bf16 as 2048 complex (even/odd packed); upper half unwritten (zero)
  #pragma unroll
  for (int j = 0; j < 8; ++j) {
    int n2 = tid + 256 * j;
    X[phys(n2)] = bf16pair_to_f2(row[n2]);
  }
  __syncthreads();

  fft_forward(X, tid);

  // Hermitian unpack -> pointwise multiply -> repack for inverse
  const float2* Kc = Kf + (size_t)c * KST;
  for (int k = tid; k <= 2048; k += 256) {
    int kq = (4096 - k) & 4095;
    int p = phys(br12(k));
    int q = phys(br12(kq));
    float2 Zk = X[p], Zq = X[q];
    float c_, s_; __sincosf((float)k * (3.14159265358979e0f / 4096.0f), &s_, &c_);
    float2 Xk, Xm;
    unpack_pair(Zk, Zq, c_, s_, Xk, Xm);
    float2 Yk = cmulf(Xk, Kc[k]);
    float2 Ym = cmulf(Xm, Kc[4096 - k]);
    float Ax = 0.5f*(Yk.x + Ym.x), Ay = 0.5f*(Yk.y - Ym.y);
    float Bx = 0.5f*(Yk.x - Ym.x), By = 0.5f*(Yk.y + Ym.y);
    X[p] = make_float2(Ax - c_*By - s_*Bx,  Ay + c_*Bx - s_*By);
    X[q] = make_float2(Ax + c_*By + s_*Bx, -Ay + c_*Bx - s_*By);
  }
  __syncthreads();

  fft_inverse(X, tid);

  #pragma unroll
  for (int j = 0; j < 16; ++j) {
    int n2 = tid + 256 * j;
    row[n2] = f2_to_bf16pair(X[phys(n2)]);
  }
}

// ---------------- kernel 4: yt[B,CH,L] -> y[B,L,CH], fused + u*bias ---------
__global__ __launch_bounds__(256) void transpose_out(
    const __hip_bfloat16* __restrict__ yt, const float* __restrict__ u,
    const float* __restrict__ bias, float* __restrict__ y) {
  __shared__ float tile[64][65];
  int i0 = blockIdx.x * 64, c0 = blockIdx.y * 64, b = blockIdx.z;
  int tr = threadIdx.x >> 6, tc = threadIdx.x & 63;
  const __hip_bfloat16* yp = yt + ((size_t)b * NCH + c0) * SEQ + i0;
  for (int r = tr; r < 64; r += 4) tile[r][tc] = __bfloat162float(yp[(size_t)r * SEQ + tc]);
  __syncthreads();
  float bi = bias[c0 + tc];
  const float* up = u + ((size_t)b * SEQ + i0) * NCH + c0;
  float* op = y + ((size_t)b * SEQ + i0) * NCH + c0;
  for (int r = tr; r < 64; r += 4)
    op[(size_t)r * NCH + tc] = tile[tc][r] + up[(size_t)r * NCH + tc] * bi;
}

extern "C" void kernel_launch(void* const* d_in, const int* in_sizes, int n_in,
                              void* d_out, int out_size, void* d_ws, size_t ws_size,
                              hipStream_t stream) {
  const float* u      = (const float*)d_in[0];
  const float* w1     = (const float*)d_in[1];
  const float* b1     = (const float*)d_in[2];
  const float* w2     = (const float*)d_in[3];
  const float* b2     = (const float*)d_in[4];
  const float* w3     = (const float*)d_in[5];
  const float* b3     = (const float*)d_in[6];
  const float* freq   = (const float*)d_in[7];
  const float* deltas = (const float*)d_in[8];
  const float* bias   = (const float*)d_in[9];
  float* out = (float*)d_out;

  __hip_bfloat16* ut = (__hip_bfloat16*)d_ws;                         // 100,663,296 B
  float2* Kf = (float2*)((char*)d_ws + (size_t)NB * NCH * SEQ * 2);   // 25,214,976 B

  filter_fft_kernel<<<dim3(NCH), dim3(256), 0, stream>>>(w1, b1, w2, b2, w3, b3, freq, deltas, Kf);
  transpose_in<<<dim3(SEQ / 64, NCH / 64, NB), dim3(256), 0, stream>>>(u, ut);
  conv_kernel<<<dim3(NCH, NB), dim3(256), 0, stream>>>(ut, Kf);
  transpose_out<<<dim3(SEQ / 64, NCH / 64, NB), dim3(256), 0, stream>>>(ut, u, bias, out);
}